// Round 7
// baseline (721.713 us; speedup 1.0000x reference)
//
#include <hip/hip_runtime.h>

// Levelized STA, persistent cooperative kernel + PADDED atomic target.
// R2/R4/R5/R6 all floor at ~16us/step with occupancy 24->97%, VALU 2%,
// HBM 12%: the shared resource is 262K scatter-atomics/step into a dense
// 512KB row (16 dests/64B line x 2 arcs = ~32 line-colliding atomics).
// R7 A/B: spread required at stride 32B (2 dests/line, ~8x fewer collisions).
//
// d_out (floats): [0,LP) arrival | [LP,2LP) required | [2LP,3LP) slack
//                 | [3LP..) mask as 0.0/1.0
// d_ws (ints): [0) padded req LP*8 | esrc NARC | bits 32768 | barrier words
constexpr int L = 32;
constexpr int P = 131072;        // 2^17
constexpr int LP = L * P;
constexpr int NARC = (L - 1) * P * 2;  // 8,126,464 (div by 4)
constexpr int NNETS = 1000000;
constexpr int NBLK = 2048;
constexpr int TPB = 256;
constexpr int NTHR = NBLK * TPB;  // 524288 = 4P; LP/NTHR = 8
constexpr float TPER = 10.0f;
constexpr float NEGV = -1e30f;
constexpr int SRCMASK = P - 1;
constexpr int RSTR = 8;           // padded req stride in ints (32B)

// ws layout (int offsets)
constexpr size_t WS_RQP = 0;                                // 33,554,432
constexpr size_t WS_ESRC = WS_RQP + (size_t)LP * RSTR;
constexpr size_t WS_BITS = WS_ESRC + NARC;                  // 32768 words
constexpr size_t WS_CNT1 = WS_BITS + 32768;                 // 64 ctrs x16
constexpr size_t WS_CNT2 = WS_CNT1 + 1024 + 16;
constexpr size_t WS_FLAG = WS_CNT2 + 16;
constexpr size_t WS_END = WS_FLAG + 16;

__device__ __forceinline__ float agent_load_f(const float* p) {
  return __hip_atomic_load(p, __ATOMIC_RELAXED, __HIP_MEMORY_SCOPE_AGENT);
}
__device__ __forceinline__ void agent_store_f(float* p, float v) {
  __hip_atomic_store(p, v, __ATOMIC_RELAXED, __HIP_MEMORY_SCOPE_AGENT);
}

// Float atomic-min via int-min (>=0) / uint-max (<0); exact all sign mixes.
__device__ __forceinline__ void atomic_min_f32(float* addr, float val) {
  if (val >= 0.0f) {
    atomicMin(reinterpret_cast<int*>(addr), __float_as_int(val));
  } else {
    atomicMax(reinterpret_cast<unsigned int*>(addr), __float_as_uint(val));
  }
}

// Two-level grid barrier (R6-proven): monotonic epoch, no counter reset.
__device__ __forceinline__ void gbar(int* ws, int epoch) {
  asm volatile("s_waitcnt vmcnt(0)" ::: "memory");
  __syncthreads();
  if (threadIdx.x == 0) {
    int* flag = ws + WS_FLAG;
    int* cnt1 = ws + WS_CNT1 + ((blockIdx.x >> 5) << 4);
    int o1 = __hip_atomic_fetch_add(cnt1, 1, __ATOMIC_RELAXED,
                                    __HIP_MEMORY_SCOPE_AGENT);
    if (o1 == epoch * 32 - 1) {
      int o2 = __hip_atomic_fetch_add(ws + WS_CNT2, 1, __ATOMIC_RELAXED,
                                      __HIP_MEMORY_SCOPE_AGENT);
      if (o2 == epoch * 64 - 1)
        __hip_atomic_store(flag, epoch, __ATOMIC_RELAXED,
                           __HIP_MEMORY_SCOPE_AGENT);
    }
    while (__hip_atomic_load(flag, __ATOMIC_RELAXED,
                             __HIP_MEMORY_SCOPE_AGENT) < epoch) {
      __builtin_amdgcn_s_sleep(2);
    }
  }
  __syncthreads();
}

// Setup kernel 1: net-ignore bit-vector via wave ballot (plain stores;
// kernel boundary provides coherence).
__global__ __launch_bounds__(TPB) void sta_bits(const int* __restrict__ mask,
                                                int* __restrict__ ws) {
  const int t = blockIdx.x * TPB + threadIdx.x;
  const int lane = threadIdx.x & 63;
  int* bits = ws + WS_BITS;
#pragma unroll
  for (int j = 0; j < 2; ++j) {
    const int idx = j * NTHR + t;
    int mv = 0;
    if (idx < NNETS) mv = mask[idx];
    unsigned long long bal = __ballot(mv != 0);
    if (lane == 0)
      *reinterpret_cast<unsigned long long*>(bits +
                                             ((j * NTHR + (t & ~63)) >> 5)) = bal;
  }
}

// Setup kernel 2: esrc = src | (ignored<<31); bits probes are L2-resident
// (125KB) instead of R4's 4MB random mask gathers.
__global__ __launch_bounds__(256) void sta_esrc(const int* __restrict__ src,
                                                const int* __restrict__ net,
                                                int* __restrict__ ws) {
  const int a4 = (blockIdx.x * blockDim.x + threadIdx.x) * 4;
  const int* bits = ws + WS_BITS;
  if (a4 < NARC) {
    int4 s = *reinterpret_cast<const int4*>(src + a4);
    int4 n = *reinterpret_cast<const int4*>(net + a4);
    s.x |= ((bits[n.x >> 5] >> (n.x & 31)) & 1) << 31;
    s.y |= ((bits[n.y >> 5] >> (n.y & 31)) & 1) << 31;
    s.z |= ((bits[n.z >> 5] >> (n.z & 31)) & 1) << 31;
    s.w |= ((bits[n.w >> 5] >> (n.w & 31)) & 1) << 31;
    *reinterpret_cast<int4*>(ws + WS_ESRC + a4) = s;
  }
}

__global__ __launch_bounds__(TPB, 8) void sta_persist(
    const float* __restrict__ delays, const int* __restrict__ mask,
    float* __restrict__ out, int* __restrict__ ws) {
  const int t = blockIdx.x * TPB + threadIdx.x;  // [0, 4P)
  const int lane = threadIdx.x & 63;
  float* arr = out;
  float* reqo = out + LP;
  float* slk = out + 2 * LP;
  float* mf = out + 3 * LP;
  float* rqp = reinterpret_cast<float*>(ws + WS_RQP);  // padded required
  const int* esrc = ws + WS_ESRC;

  // ---- phase 0: padded req=TPER, arr[0]=delays[0], mask->float ----
  if (t < P) agent_store_f(arr + t, delays[t]);
#pragma unroll
  for (int c = 0; c < 8; ++c)
    agent_store_f(rqp + (size_t)(c * NTHR + t) * RSTR, TPER);
  {
    const int idx = t * 2;
    if (idx < NNETS) {
      const int2 m = *reinterpret_cast<const int2*>(mask + idx);
      float2 f = {m.x ? 1.0f : 0.0f, m.y ? 1.0f : 0.0f};
      *reinterpret_cast<float2*>(mf + idx) = f;
    }
  }
  gbar(ws, 1);

  // ---- 31 fused steps, arc-parallel ----
  const int half = t >> 18;        // 0: forward, 1: backward
  const int a = t & (2 * P - 1);   // arc id
  const int p = a >> 1;            // pin

  for (int i = 1; i < L; ++i) {
    if (half == 0) {  // forward: arr[i][p] = max(valid fanin max, own delay)
      const int lf = i;
      const float d = delays[lf * P + p];
      const int s = esrc[(size_t)(lf - 1) * 2 * P + a];
      float v = arr[(size_t)(lf - 1) * P + (s & SRCMASK)] + d;
      if (s < 0) v = NEGV;
      const float vo = __shfl_xor(v, 1);
      if ((a & 1) == 0)
        agent_store_f(arr + (size_t)lf * P + p, fmaxf(fmaxf(v, vo), d));
    } else {          // backward: scatter-min into padded req[lb]
      const int lb = L - 1 - i;
      float c0 = 0.0f;
      if ((a & 1) == 0)
        c0 = agent_load_f(rqp + ((size_t)(lb + 1) * P + p) * RSTR) -
             delays[(lb + 1) * P + p];
      const float c = __shfl(c0, lane & 62);
      const int s = esrc[(size_t)lb * 2 * P + a];
      if (s >= 0)
        atomic_min_f32(rqp + ((size_t)lb * P + s) * RSTR, c);
    }
    gbar(ws, i + 1);
  }

  // ---- epilogue: densify required, slack = required - arrival ----
#pragma unroll
  for (int c = 0; c < 8; ++c) {
    const int idx = c * NTHR + t;
    const float rv = agent_load_f(rqp + (size_t)idx * RSTR);
    const float av = arr[idx];  // fresh-only: normal cached
    reqo[idx] = rv;
    slk[idx] = rv - av;
  }
}

// ---- proven R2 fallback chain if cooperative launch fails ----
__global__ __launch_bounds__(256) void sta_init(
    const float* __restrict__ delays, const int* __restrict__ mask,
    float* __restrict__ out) {
  int i4 = (blockIdx.x * blockDim.x + threadIdx.x) * 4;
  if (i4 < LP) {
    float4 ten = {TPER, TPER, TPER, TPER};
    *reinterpret_cast<float4*>(out + LP + i4) = ten;
    if (i4 < P)
      *reinterpret_cast<float4*>(out + i4) =
          *reinterpret_cast<const float4*>(delays + i4);
  }
  if (i4 < NNETS) {
    int4 m = *reinterpret_cast<const int4*>(mask + i4);
    float4 f = {(float)(m.x != 0), (float)(m.y != 0), (float)(m.z != 0),
                (float)(m.w != 0)};
    *reinterpret_cast<float4*>(out + 3 * LP + i4) = f;
  }
}

__global__ __launch_bounds__(256) void sta_step_direct(
    const float* __restrict__ delays, const int* __restrict__ src,
    const int* __restrict__ net, const int* __restrict__ mask,
    float* __restrict__ out, int i) {
  const int p = blockIdx.x * blockDim.x + threadIdx.x;
  float* arr = out;
  float* req = out + LP;
  const int lf = i, lb = L - 1 - i;
  {
    const float d = delays[lf * P + p];
    const int2 s = *reinterpret_cast<const int2*>(src + (size_t)(lf - 1) * P * 2 + p * 2);
    const int2 n = *reinterpret_cast<const int2*>(net + (size_t)(lf - 1) * P * 2 + p * 2);
    const float* ap = arr + (lf - 1) * P;
    const float v0 = mask[n.x] ? NEGV : ap[s.x] + d;
    const float v1 = mask[n.y] ? NEGV : ap[s.y] + d;
    arr[lf * P + p] = fmaxf(fmaxf(v0, v1), d);
  }
  {
    const float c = req[(lb + 1) * P + p] - delays[(lb + 1) * P + p];
    const int2 s = *reinterpret_cast<const int2*>(src + (size_t)lb * P * 2 + p * 2);
    const int2 n = *reinterpret_cast<const int2*>(net + (size_t)lb * P * 2 + p * 2);
    float* rp = req + lb * P;
    if (!mask[n.x]) atomic_min_f32(rp + s.x, c);
    if (!mask[n.y]) atomic_min_f32(rp + s.y, c);
  }
}

__global__ __launch_bounds__(256) void sta_slack(float* __restrict__ out) {
  int i4 = (blockIdx.x * blockDim.x + threadIdx.x) * 4;
  if (i4 < LP) {
    float4 a = *reinterpret_cast<const float4*>(out + i4);
    float4 r = *reinterpret_cast<const float4*>(out + LP + i4);
    float4 s = {r.x - a.x, r.y - a.y, r.z - a.z, r.w - a.w};
    *reinterpret_cast<float4*>(out + 2 * LP + i4) = s;
  }
}

extern "C" void kernel_launch(void* const* d_in, const int* in_sizes, int n_in,
                              void* d_out, int out_size, void* d_ws, size_t ws_size,
                              hipStream_t stream) {
  const float* delays = (const float*)d_in[0];
  const int* src = (const int*)d_in[1];
  const int* net = (const int*)d_in[2];
  const int* mask = (const int*)d_in[3];  // JAX bool delivered as int32
  float* out = (float*)d_out;
  int* ws = (int*)d_ws;

  if (ws_size >= WS_END * sizeof(int)) {
    // zero barrier counters + flag (ws poisoned 0xAA before every call)
    hipMemsetAsync((char*)d_ws + WS_CNT1 * sizeof(int), 0,
                   (WS_END - WS_CNT1) * sizeof(int), stream);
    sta_bits<<<NBLK, TPB, 0, stream>>>(mask, ws);
    sta_esrc<<<NARC / 4 / 256, 256, 0, stream>>>(src, net, ws);
    void* args[] = {(void*)&delays, (void*)&mask, (void*)&out, (void*)&ws};
    hipError_t e = hipLaunchCooperativeKernel((const void*)sta_persist,
                                              dim3(NBLK), dim3(TPB), args, 0,
                                              stream);
    if (e == hipSuccess) return;
    (void)hipGetLastError();  // clear; fall through to proven path
  }
  sta_init<<<LP / 1024, 256, 0, stream>>>(delays, mask, out);
  for (int i = 1; i < L; ++i)
    sta_step_direct<<<P / 256, 256, 0, stream>>>(delays, src, net, mask, out, i);
  sta_slack<<<LP / 1024, 256, 0, stream>>>(out);
}